// Round 1
// baseline (561.681 us; speedup 1.0000x reference)
//
#include <hip/hip_runtime.h>

// Problem constants
#define N4 4096
#define FF 32
#define KK 6
#define OO 128
#define BB 4

typedef __attribute__((ext_vector_type(8))) short  short8;   // 8 bf16 (4 VGPRs) MFMA A/B frag
typedef __attribute__((ext_vector_type(4))) float  f32x4;    // MFMA C/D frag
typedef __attribute__((ext_vector_type(4))) int    i32x4;    // 16B copy
typedef __attribute__((ext_vector_type(2))) unsigned int u32x2;

__device__ __forceinline__ float b2f(unsigned short h) {
    union { float f; unsigned u; } v; v.u = ((unsigned)h) << 16; return v.f;
}
__device__ __forceinline__ unsigned short f2b(float f) {
    union { float f; unsigned u; } v; v.f = f;
    unsigned r = (v.u + 0x7FFFu + ((v.u >> 16) & 1u)) >> 16;
    return (unsigned short)r;
}

// ---------------------------------------------------------------------------
// Wc[k][f][o] = bf16(theta[k] * W[k][f][o]);  K*F*O = 24576 elems, grid 96x256
__global__ __launch_bounds__(256) void make_wc(const float* __restrict__ W,
                                               const float* __restrict__ theta,
                                               unsigned short* __restrict__ Wc) {
    int idx = blockIdx.x * 256 + threadIdx.x;
    int k = idx >> 12;                 // F*O = 4096
    Wc[idx] = f2b(theta[k] * W[idx]);
}

// ---------------------------------------------------------------------------
// x [B][N][F] f32  ->  T0 [B][F][N] bf16 (transposed).  grid B*(N/64)=256, 256 thr
__global__ __launch_bounds__(256) void x_to_t(const float* __restrict__ x,
                                              unsigned short* __restrict__ T0) {
    __shared__ __align__(16) unsigned short Ol[32][72];
    int tid = threadIdx.x, bid = blockIdx.x;
    int b = bid >> 6; long n0 = (long)(bid & 63) * 64;
    int nl = tid >> 2, fg = (tid & 3) * 8;
    const float* src = x + ((long)b * N4 + n0 + nl) * FF + fg;
    f32x4 v0 = *(const f32x4*)src;
    f32x4 v1 = *(const f32x4*)(src + 4);
#pragma unroll
    for (int e = 0; e < 4; ++e) {
        Ol[fg + e][nl]     = f2b(v0[e]);
        Ol[fg + 4 + e][nl] = f2b(v1[e]);
    }
    __syncthreads();
    int f = tid >> 3, col = (tid & 7) * 8;
    *(i32x4*)(T0 + ((long)b * FF + f) * N4 + n0 + col) = *(const i32x4*)&Ol[f][col];
}

// ---------------------------------------------------------------------------
// GEMM pass: P[s][b][m0..m0+128][0..32] = L_b[m-rows, kchunk] @ T_{k-1}[kchunk, F]
// MODE 0: read f32 L, write bf16 L copy.  MODE 1: read bf16 L.  MODE 2: f32 only.
// grid = B * 32 * SPLITK(4) = 512 blocks, 256 threads (4 waves).
template <int MODE>
__global__ __launch_bounds__(256) void gemm_pass(const float* __restrict__ Lf,
                                                 const unsigned short* __restrict__ Lb,
                                                 unsigned short* __restrict__ LbOut,
                                                 const unsigned short* __restrict__ Tt, // [B][F][N] bf16
                                                 float* __restrict__ P) {               // [4][B][N][F]
    __shared__ __align__(16) unsigned short Al[128][72];
    __shared__ __align__(16) unsigned short Bl[32][72];
    int tid = threadIdx.x, bid = blockIdx.x;
    int s = bid & 3, mb = (bid >> 2) & 31, b = bid >> 7;
    long m0 = (long)mb * 128;
    long k0 = (long)s * 1024;
    int wave = tid >> 6, lane = tid & 63, quad = lane >> 4, l16 = lane & 15;

    f32x4 acc00 = {0.f,0.f,0.f,0.f}, acc01 = {0.f,0.f,0.f,0.f};
    f32x4 acc10 = {0.f,0.f,0.f,0.f}, acc11 = {0.f,0.f,0.f,0.f};

    for (int kc = 0; kc < 1024; kc += 64) {
        // ---- stage A tile (128 x 64) ----
        if (MODE != 1) {
            const float* src = Lf + (long)b * N4 * N4;
#pragma unroll
            for (int it = 0; it < 8; ++it) {
                int row = it * 16 + (tid >> 4);
                int col = (tid & 15) * 4;
                long g = (m0 + row) * (long)N4 + k0 + kc + col;
                f32x4 v = *(const f32x4*)(src + g);
                u32x2 pk;
                pk[0] = (unsigned)f2b(v[0]) | ((unsigned)f2b(v[1]) << 16);
                pk[1] = (unsigned)f2b(v[2]) | ((unsigned)f2b(v[3]) << 16);
                *(u32x2*)&Al[row][col] = pk;
                if (MODE == 0)
                    *(u32x2*)(LbOut + (long)b * N4 * N4 + g) = pk;
            }
        } else {
            const unsigned short* src = Lb + (long)b * N4 * N4;
#pragma unroll
            for (int it = 0; it < 4; ++it) {
                int row = it * 32 + (tid >> 3);
                int col = (tid & 7) * 8;
                long g = (m0 + row) * (long)N4 + k0 + kc + col;
                *(i32x4*)&Al[row][col] = *(const i32x4*)(src + g);
            }
        }
        // ---- stage B tile: Tt[b][f][k0+kc .. +64] -> Bl[f][64] ----
        {
            int f = tid >> 3, col = (tid & 7) * 8;
            *(i32x4*)&Bl[f][col] =
                *(const i32x4*)(Tt + ((long)b * FF + f) * N4 + k0 + kc + col);
        }
        __syncthreads();
#pragma unroll
        for (int kk = 0; kk < 64; kk += 32) {
            short8 a0 = *(const short8*)&Al[wave * 32 + l16][kk + quad * 8];
            short8 a1 = *(const short8*)&Al[wave * 32 + 16 + l16][kk + quad * 8];
            short8 b0 = *(const short8*)&Bl[l16][kk + quad * 8];
            short8 b1 = *(const short8*)&Bl[16 + l16][kk + quad * 8];
            acc00 = __builtin_amdgcn_mfma_f32_16x16x32_bf16(a0, b0, acc00, 0, 0, 0);
            acc01 = __builtin_amdgcn_mfma_f32_16x16x32_bf16(a0, b1, acc01, 0, 0, 0);
            acc10 = __builtin_amdgcn_mfma_f32_16x16x32_bf16(a1, b0, acc10, 0, 0, 0);
            acc11 = __builtin_amdgcn_mfma_f32_16x16x32_bf16(a1, b1, acc11, 0, 0, 0);
        }
        __syncthreads();
    }
    // ---- epilogue: store f32 partial.  D frag: row=(lane>>4)*4+r, col=lane&15
    float* Pp = P + (((long)s * BB + b) * N4 + m0) * FF;
#pragma unroll
    for (int r = 0; r < 4; ++r) {
        int row0 = wave * 32 + quad * 4 + r;
        int row1 = row0 + 16;
        Pp[(long)row0 * FF + l16]      = acc00[r];
        Pp[(long)row0 * FF + 16 + l16] = acc01[r];
        Pp[(long)row1 * FF + l16]      = acc10[r];
        Pp[(long)row1 * FF + 16 + l16] = acc11[r];
    }
}

// ---------------------------------------------------------------------------
// T_k = a * (sum_s P[s]) + c * T_{k-2};  writes bf16 transposed [B][F][N]
// grid B*(N/64)=256, 256 thr
__global__ __launch_bounds__(256) void reduce_pass(const float* __restrict__ P,
                                                   const unsigned short* __restrict__ Tpp,
                                                   unsigned short* __restrict__ Tout,
                                                   float a, float c) {
    __shared__ __align__(16) unsigned short Tpl[32][72];
    __shared__ __align__(16) unsigned short Ol[32][72];
    int tid = threadIdx.x, bid = blockIdx.x;
    int b = bid >> 6; long n0 = (long)(bid & 63) * 64;
    if (Tpp) {
        int f = tid >> 3, col = (tid & 7) * 8;
        *(i32x4*)&Tpl[f][col] = *(const i32x4*)(Tpp + ((long)b * FF + f) * N4 + n0 + col);
    }
    __syncthreads();
    int nl = tid >> 2, fg = (tid & 3) * 8;
    const float* p0 = P + ((long)b * N4 + n0 + nl) * FF + fg;
    float sum[8];
#pragma unroll
    for (int e = 0; e < 8; ++e) sum[e] = 0.f;
#pragma unroll
    for (int s = 0; s < 4; ++s) {
        const float* ps = p0 + (long)s * BB * N4 * FF;
        f32x4 v0 = *(const f32x4*)ps;
        f32x4 v1 = *(const f32x4*)(ps + 4);
#pragma unroll
        for (int e = 0; e < 4; ++e) { sum[e] += v0[e]; sum[4 + e] += v1[e]; }
    }
#pragma unroll
    for (int e = 0; e < 8; ++e) {
        float val = a * sum[e];
        if (Tpp) val += c * b2f(Tpl[fg + e][nl]);
        Ol[fg + e][nl] = f2b(val);
    }
    __syncthreads();
    int f = tid >> 3, col = (tid & 7) * 8;
    *(i32x4*)(Tout + ((long)b * FF + f) * N4 + n0 + col) = *(const i32x4*)&Ol[f][col];
}

// ---------------------------------------------------------------------------
// out[b][n][o] = sum_k sum_f T_k[b][f][n] * Wc[k][f][o]   (Wc already has theta)
// grid = B * (N/64) * 2(o-halves) = 512 blocks, 256 thr
__global__ __launch_bounds__(256) void proj(const unsigned short* __restrict__ T, // [K][B][F][N]
                                            const unsigned short* __restrict__ Wc, // [K*F][O]
                                            float* __restrict__ out) {
    __shared__ __align__(16) unsigned short Tl[192][72];
    __shared__ __align__(16) unsigned short Wl[192][64];
    int tid = threadIdx.x, bid = blockIdx.x;
    int b = bid >> 7; int rem = bid & 127;
    long n0 = (long)(rem >> 1) * 64; int oh = rem & 1;
#pragma unroll
    for (int it = 0; it < 6; ++it) {
        int row = it * 32 + (tid >> 3);    // kf index
        int col = (tid & 7) * 8;
        int k = row >> 5, f = row & 31;
        *(i32x4*)&Tl[row][col] =
            *(const i32x4*)(T + (((long)k * BB + b) * FF + f) * N4 + n0 + col);
        *(i32x4*)&Wl[row][col] = *(const i32x4*)(Wc + (long)row * OO + oh * 64 + col);
    }
    __syncthreads();
    int ol = tid & 63;
    int nb = (tid >> 6) * 16;
    float acc[16];
#pragma unroll
    for (int r = 0; r < 16; ++r) acc[r] = 0.f;
    for (int kf = 0; kf < 192; ++kf) {
        float w = b2f(Wl[kf][ol]);
#pragma unroll
        for (int rv = 0; rv < 2; ++rv) {
            short8 tv = *(const short8*)&Tl[kf][nb + rv * 8];
#pragma unroll
            for (int e = 0; e < 8; ++e)
                acc[rv * 8 + e] += b2f((unsigned short)tv[e]) * w;
        }
    }
    int o = oh * 64 + ol;
#pragma unroll
    for (int r = 0; r < 16; ++r)
        out[((long)b * N4 + n0 + nb + r) * OO + o] = acc[r];
}

// ---------------------------------------------------------------------------
extern "C" void kernel_launch(void* const* d_in, const int* in_sizes, int n_in,
                              void* d_out, int out_size, void* d_ws, size_t ws_size,
                              hipStream_t stream) {
    const float* x     = (const float*)d_in[0];
    const float* L     = (const float*)d_in[1];
    const float* W     = (const float*)d_in[2];
    const float* theta = (const float*)d_in[3];
    float* out = (float*)d_out;
    char* ws = (char*)d_ws;

    const size_t LB_BYTES = (size_t)BB * N4 * N4 * 2;          // 134,217,728
    const size_t T_SLOT   = (size_t)BB * FF * N4;              // elems per slot
    const size_t T_BYTES  = (size_t)KK * T_SLOT * 2;           // 6,291,456
    const size_t P_BYTES  = (size_t)4 * BB * N4 * FF * 4;      // 8,388,608
    const size_t WC_BYTES = (size_t)KK * FF * OO * 2;          // 49,152

    bool haveL = ws_size >= LB_BYTES + T_BYTES + P_BYTES + WC_BYTES;
    size_t off = haveL ? LB_BYTES : 0;
    unsigned short* Lb = (unsigned short*)ws;
    unsigned short* T  = (unsigned short*)(ws + off);
    float*          P  = (float*)(ws + off + T_BYTES);
    unsigned short* Wc = (unsigned short*)(ws + off + T_BYTES + P_BYTES);

    make_wc<<<96, 256, 0, stream>>>(W, theta, Wc);
    x_to_t<<<256, 256, 0, stream>>>(x, T);   // slot 0 = bf16(x)^T

    // pass 1: T1 = L @ T0
    if (haveL)
        gemm_pass<0><<<512, 256, 0, stream>>>(L, nullptr, Lb, T, P);
    else
        gemm_pass<2><<<512, 256, 0, stream>>>(L, nullptr, nullptr, T, P);
    reduce_pass<<<256, 256, 0, stream>>>(P, nullptr, T + 1 * T_SLOT, 1.f, 0.f);

    // passes 2..5: T_k = 2 L @ T_{k-1} - T_{k-2}
    for (int k = 2; k < KK; ++k) {
        if (haveL)
            gemm_pass<1><<<512, 256, 0, stream>>>(nullptr, Lb, nullptr, T + (k - 1) * T_SLOT, P);
        else
            gemm_pass<2><<<512, 256, 0, stream>>>(L, nullptr, nullptr, T + (k - 1) * T_SLOT, P);
        reduce_pass<<<256, 256, 0, stream>>>(P, T + (k - 2) * T_SLOT, T + k * T_SLOT, 2.f, -1.f);
    }

    proj<<<512, 256, 0, stream>>>(T, Wc, out);
}